// Round 1
// baseline (79.940 us; speedup 1.0000x reference)
//
#include <hip/hip_runtime.h>
#include <math.h>

// ---- problem constants (from reference) ----
constexpr int NB = 32;
constexpr int NA_ = 3;
constexpr int NH_ = 64;
constexpr int NW_ = 64;
constexpr int NG_ = 24;
constexpr int NCLS_ = 80;
constexpr int NCELLS = NA_ * NH_ * NW_;   // 12288
constexpr float IGNORE_THRE_ = 0.6f;

__device__ __constant__ float c_aw[9] = {10.f,16.f,33.f,30.f,62.f,59.f,116.f,156.f,373.f};
__device__ __constant__ float c_ah[9] = {13.f,30.f,23.f,61.f,45.f,119.f,90.f,198.f,326.f};

__device__ __forceinline__ float bce(float x, float t) {
  // max(x,0) - x*t + log1p(exp(-|x|))
  return fmaxf(x, 0.f) - x * t + log1pf(expf(-fabsf(x)));
}

// ---------------------------------------------------------------------------
// Kernel 1: per-image GT processing + sparse losses (xy, wh, cls).
// One block (1 wave, 64 thr) per image.
// ws layout per image (stride 32 ints): [0]=any_valid, [1]=n_targets, [2..25]=cells
// ---------------------------------------------------------------------------
__global__ __launch_bounds__(64)
void yolo_setup(const float* __restrict__ bbox,
                const float* __restrict__ cls,
                const float* __restrict__ labels,
                const int* __restrict__ img_h,
                const int* __restrict__ img_w,
                int* __restrict__ wsI,
                float* __restrict__ out)
{
  const int b = blockIdx.x;
  const int t = threadIdx.x;

  __shared__ int   s_cell[NG_];
  __shared__ int   s_cid[NG_];
  __shared__ int   s_valid[NG_];
  __shared__ float s_upd[NG_][4];
  __shared__ float s_wv[NG_];

  const float img_area = (float)(*img_h) * (float)(*img_w);

  if (t < NG_) {
    const float* lab = labels + ((size_t)b * NG_ + t) * 5;
    const float cidf = lab[0];
    const float w = lab[3], h = lab[4];
    // anchor IoU argmax (center (0,0) boxes): inter = min(w,aw)*min(h,ah)
    int best = 0; float bestv = -1.f;
    #pragma unroll
    for (int k = 0; k < 9; ++k) {
      const float inter = fminf(w, c_aw[k]) * fminf(h, c_ah[k]);
      const float uni = w * h + c_aw[k] * c_ah[k] - inter;
      const float v = inter / uni;
      if (v > bestv) { bestv = v; best = k; }   // first-max => strict >
    }
    const int valid = (best < NA_) ? 1 : 0;     // ANCH_LO == 0
    const int tn = best % NA_;
    const float gx = lab[1] * 0.125f;
    const float gy = lab[2] * 0.125f;
    const int ti = (int)gx;
    const int tj = (int)gy;
    s_cell[t]  = valid ? (tn * (NH_ * NW_) + tj * NW_ + ti) : -1;
    s_cid[t]   = (int)cidf;
    s_valid[t] = valid;
    const float aw = c_aw[tn], ah = c_ah[tn];
    s_upd[t][0] = gx - floorf(gx);
    s_upd[t][1] = gy - floorf(gy);
    s_upd[t][2] = logf(w / aw + 1e-8f);
    s_upd[t][3] = logf(h / ah + 1e-8f);
    s_wv[t] = 2.f - w * h / img_area;
  }
  __syncthreads();

  // winner: valid and no LATER valid gt writes the same cell (last-write-wins)
  int winner = 0;
  if (t < NG_ && s_valid[t]) {
    winner = 1;
    for (int g2 = t + 1; g2 < NG_; ++g2)
      if (s_valid[g2] && s_cell[g2] == s_cell[t]) { winner = 0; break; }
  }

  const unsigned long long wm = __ballot(winner);
  const int nt = __popcll(wm);
  if (winner) {
    const int pos = __popcll(wm & ((1ull << t) - 1ull));
    wsI[b * 32 + 2 + pos] = s_cell[t];
  }
  if (t == 0) {
    int av = 0;
    for (int g = 0; g < NG_; ++g) av |= s_valid[g];
    wsI[b * 32 + 0] = av;
    wsI[b * 32 + 1] = nt;
  }

  // sparse losses at winner cells
  float acc = 0.f;
  if (winner) {
    const int cell = s_cell[t];
    const float* bb = bbox + ((size_t)b * NCELLS + cell) * 4;
    const float wv = s_wv[t];
    // loss_xy
    float l = bce(bb[0], s_upd[t][0]) + bce(bb[1], s_upd[t][1]);
    acc += wv * l;
    // 0.5 * loss_wh
    const float d2 = bb[2] - s_upd[t][2];
    const float d3 = bb[3] - s_upd[t][3];
    acc += 0.5f * wv * (d2 * d2 + d3 * d3);
    // loss_cls: sum_c bce(x,0) - sum_{distinct cid at this cell} x[cid]
    const float* cr = cls + ((size_t)b * NCELLS + cell) * NCLS_;
    float lc = 0.f;
    for (int c = 0; c < NCLS_; ++c) {
      const float x = cr[c];
      lc += fmaxf(x, 0.f) + log1pf(expf(-fabsf(x)));
    }
    for (int g2 = 0; g2 < NG_; ++g2) {
      if (s_valid[g2] && s_cell[g2] == cell) {
        int first = 1;
        for (int g3 = 0; g3 < g2; ++g3)
          if (s_valid[g3] && s_cell[g3] == cell && s_cid[g3] == s_cid[g2]) { first = 0; break; }
        if (first) lc -= cr[s_cid[g2]];
      }
    }
    acc += lc;
  }

  // wave-64 reduce
  #pragma unroll
  for (int off = 32; off; off >>= 1) acc += __shfl_down(acc, off, 64);
  if (t == 0) atomicAdd(out, acc);
}

// ---------------------------------------------------------------------------
// Kernel 2: dense conf loss. grid = (48, 32), 256 thr; one thread per cell.
// ---------------------------------------------------------------------------
__global__ __launch_bounds__(256)
void yolo_conf(const float* __restrict__ bbox,
               const float* __restrict__ conf,
               const float* __restrict__ labels,
               const int* __restrict__ wsI,
               float* __restrict__ out)
{
  const int b = blockIdx.y;
  const int t = threadIdx.x;
  const int cell = blockIdx.x * 256 + t;   // 48*256 == 12288 exactly

  __shared__ float4 s_gt[NG_];
  __shared__ int    s_tc[NG_];
  __shared__ int    s_nt, s_av;

  if (t < NG_) {
    const float* lab = labels + ((size_t)b * NG_ + t) * 5;
    s_gt[t] = make_float4(lab[1], lab[2], lab[3], lab[4]);
  }
  if (t >= 64 && t < 64 + NG_) s_tc[t - 64] = wsI[b * 32 + 2 + (t - 64)];
  if (t == 32) s_av = wsI[b * 32 + 0];
  if (t == 33) s_nt = wsI[b * 32 + 1];
  __syncthreads();

  const int a  = cell >> 12;
  const int hw = cell & 4095;
  const int h  = hw >> 6;
  const int w  = hw & 63;

  const float4 bb = *reinterpret_cast<const float4*>(bbox + ((size_t)b * NCELLS + cell) * 4);
  const float  cf = conf[(size_t)b * NCELLS + cell];

  const float px = (1.f / (1.f + expf(-bb.x)) + (float)w) * 8.f;
  const float py = (1.f / (1.f + expf(-bb.y)) + (float)h) * 8.f;
  const float pw = expf(bb.z) * c_aw[a];
  const float ph = expf(bb.w) * c_ah[a];
  const float p_l = px - pw * 0.5f, p_r = px + pw * 0.5f;
  const float p_t = py - ph * 0.5f, p_b = py + ph * 0.5f;
  const float p_area = pw * ph;

  float maxiou = 0.f;
  #pragma unroll 4
  for (int g = 0; g < NG_; ++g) {
    const float4 gt = s_gt[g];
    const float g_l = gt.x - gt.z * 0.5f, g_r = gt.x + gt.z * 0.5f;
    const float g_t = gt.y - gt.w * 0.5f, g_b = gt.y + gt.w * 0.5f;
    const float iw = fminf(p_r, g_r) - fmaxf(p_l, g_l);
    const float ih = fminf(p_b, g_b) - fmaxf(p_t, g_t);
    const float inter = fmaxf(iw, 0.f) * fmaxf(ih, 0.f);
    const float uni = p_area + gt.z * gt.w - inter;
    maxiou = fmaxf(maxiou, inter / uni);
  }

  int gm = 0;
  const int nt = s_nt;
  for (int g = 0; g < nt; ++g) gm |= (s_tc[g] == cell);

  const int mask = gm | (!s_av) | (maxiou < IGNORE_THRE_);
  const float tgt = gm ? 1.f : 0.f;
  float v = mask ? bce(cf, tgt) : 0.f;

  // block reduce: wave-64 shfl then LDS
  #pragma unroll
  for (int off = 32; off; off >>= 1) v += __shfl_down(v, off, 64);
  __shared__ float s_part[4];
  const int wave = t >> 6, lane = t & 63;
  if (lane == 0) s_part[wave] = v;
  __syncthreads();
  if (t == 0) {
    atomicAdd(out, s_part[0] + s_part[1] + s_part[2] + s_part[3]);
  }
}

extern "C" void kernel_launch(void* const* d_in, const int* in_sizes, int n_in,
                              void* d_out, int out_size, void* d_ws, size_t ws_size,
                              hipStream_t stream) {
  const float* bbox   = (const float*)d_in[0];
  const float* conf   = (const float*)d_in[1];
  const float* cls    = (const float*)d_in[2];
  const float* labels = (const float*)d_in[3];
  const int*   img_h  = (const int*)d_in[4];
  const int*   img_w  = (const int*)d_in[5];

  float* out = (float*)d_out;
  int*   wsI = (int*)d_ws;

  hipMemsetAsync(out, 0, sizeof(float), stream);

  yolo_setup<<<dim3(NB), dim3(64), 0, stream>>>(bbox, cls, labels, img_h, img_w, wsI, out);
  yolo_conf<<<dim3(NCELLS / 256, NB), dim3(256), 0, stream>>>(bbox, conf, labels, wsI, out);
}

// Round 2
// 64.258 us; speedup vs baseline: 1.2441x; 1.2441x over previous
//
#include <hip/hip_runtime.h>
#include <math.h>

// ---- problem constants (from reference) ----
constexpr int NB = 32;
constexpr int NA_ = 3;
constexpr int NH_ = 64;
constexpr int NW_ = 64;
constexpr int NG_ = 24;
constexpr int NCLS_ = 80;
constexpr int NCELLS = NA_ * NH_ * NW_;   // 12288
constexpr int NBX = NCELLS / 256;         // 48
constexpr float IGNORE_THRE_ = 0.6f;

__device__ __constant__ float c_aw[9] = {10.f,16.f,33.f,30.f,62.f,59.f,116.f,156.f,373.f};
__device__ __constant__ float c_ah[9] = {13.f,30.f,23.f,61.f,45.f,119.f,90.f,198.f,326.f};

__device__ __forceinline__ float bce(float x, float t) {
  // max(x,0) - x*t + log1p(exp(-|x|))
  return fmaxf(x, 0.f) - x * t + log1pf(expf(-fabsf(x)));
}

// ---------------------------------------------------------------------------
// Kernel 1: fused GT processing + dense conf loss + sparse (xy,wh,cls) loss.
// grid = (48, 32), 256 threads; one thread per cell. Each block redundantly
// processes the 24 GTs (cheap, L2-cached) so there is no inter-kernel
// dependency and no atomics: block partial -> wsF[b*48 + bx].
// ---------------------------------------------------------------------------
__global__ __launch_bounds__(256)
void yolo_main(const float* __restrict__ bbox,
               const float* __restrict__ conf,
               const float* __restrict__ cls,
               const float* __restrict__ labels,
               const int* __restrict__ img_h,
               const int* __restrict__ img_w,
               float* __restrict__ wsF)
{
  const int b = blockIdx.y;
  const int t = threadIdx.x;
  const int cell = blockIdx.x * 256 + t;   // 48*256 == 12288 exactly

  __shared__ float4 s_gt[NG_];
  __shared__ int   s_cell[NG_];
  __shared__ int   s_cid[NG_];
  __shared__ int   s_valid[NG_];
  __shared__ int   s_win[NG_];
  __shared__ float s_upd[NG_][4];
  __shared__ float s_wv[NG_];
  __shared__ int   s_av;

  if (t < NG_) {
    const float* lab = labels + ((size_t)b * NG_ + t) * 5;
    const float cidf = lab[0];
    const float x = lab[1], y = lab[2], w = lab[3], h = lab[4];
    s_gt[t] = make_float4(x, y, w, h);
    // anchor IoU argmax (center (0,0) boxes): inter = min(w,aw)*min(h,ah)
    int best = 0; float bestv = -1.f;
    #pragma unroll
    for (int k = 0; k < 9; ++k) {
      const float inter = fminf(w, c_aw[k]) * fminf(h, c_ah[k]);
      const float uni = w * h + c_aw[k] * c_ah[k] - inter;
      const float v = inter / uni;
      if (v > bestv) { bestv = v; best = k; }   // first-max => strict >
    }
    const int valid = (best < NA_) ? 1 : 0;     // ANCH_LO == 0
    const int tn = best % NA_;
    const float gx = x * 0.125f, gy = y * 0.125f;
    const int ti = (int)gx, tj = (int)gy;
    s_cell[t]  = valid ? (tn * (NH_ * NW_) + tj * NW_ + ti) : -1;
    s_cid[t]   = (int)cidf;
    s_valid[t] = valid;
    const float aw = c_aw[tn], ah = c_ah[tn];
    s_upd[t][0] = gx - floorf(gx);
    s_upd[t][1] = gy - floorf(gy);
    s_upd[t][2] = logf(w / aw + 1e-8f);
    s_upd[t][3] = logf(h / ah + 1e-8f);
    const float img_area = (float)(*img_h) * (float)(*img_w);
    s_wv[t] = 2.f - w * h / img_area;
  }
  __syncthreads();

  // winner: valid and no LATER valid gt writes the same cell (last-write-wins)
  if (t < NG_) {
    int win = 0;
    if (s_valid[t]) {
      win = 1;
      for (int g2 = t + 1; g2 < NG_; ++g2)
        if (s_valid[g2] && s_cell[g2] == s_cell[t]) { win = 0; break; }
    }
    s_win[t] = win;
  }
  if (t == 32) {
    int av = 0;
    for (int g = 0; g < NG_; ++g) av |= s_valid[g];
    s_av = av;
  }
  __syncthreads();

  // ---- dense conf loss for this thread's cell ----
  const int a  = cell >> 12;
  const int hw = cell & 4095;
  const int hh = hw >> 6;
  const int ww = hw & 63;

  const float4 bb = *reinterpret_cast<const float4*>(bbox + ((size_t)b * NCELLS + cell) * 4);
  const float  cf = conf[(size_t)b * NCELLS + cell];

  const float px = (1.f / (1.f + expf(-bb.x)) + (float)ww) * 8.f;
  const float py = (1.f / (1.f + expf(-bb.y)) + (float)hh) * 8.f;
  const float pw = expf(bb.z) * c_aw[a];
  const float ph = expf(bb.w) * c_ah[a];
  const float p_l = px - pw * 0.5f, p_r = px + pw * 0.5f;
  const float p_t = py - ph * 0.5f, p_b = py + ph * 0.5f;
  const float p_area = pw * ph;

  float maxiou = 0.f;
  #pragma unroll 4
  for (int g = 0; g < NG_; ++g) {
    const float4 gt = s_gt[g];
    const float g_l = gt.x - gt.z * 0.5f, g_r = gt.x + gt.z * 0.5f;
    const float g_t = gt.y - gt.w * 0.5f, g_b = gt.y + gt.w * 0.5f;
    const float iw = fminf(p_r, g_r) - fmaxf(p_l, g_l);
    const float ih = fminf(p_b, g_b) - fmaxf(p_t, g_t);
    const float inter = fmaxf(iw, 0.f) * fmaxf(ih, 0.f);
    const float uni = p_area + gt.z * gt.w - inter;
    maxiou = fmaxf(maxiou, inter / uni);
  }

  int gm = 0;
  #pragma unroll
  for (int g = 0; g < NG_; ++g) gm |= (s_win[g] & (s_cell[g] == cell));

  const int mask = gm | (!s_av) | (maxiou < IGNORE_THRE_);
  float v = mask ? bce(cf, gm ? 1.f : 0.f) : 0.f;

  // ---- sparse losses (xy, wh, cls) at winner cells; only bx==0 blocks ----
  if (blockIdx.x == 0 && t < NG_ && s_win[t]) {
    const int c0 = s_cell[t];
    const float* bp = bbox + ((size_t)b * NCELLS + c0) * 4;
    const float wv = s_wv[t];
    float acc = wv * (bce(bp[0], s_upd[t][0]) + bce(bp[1], s_upd[t][1]));
    const float d2 = bp[2] - s_upd[t][2];
    const float d3 = bp[3] - s_upd[t][3];
    acc += 0.5f * wv * (d2 * d2 + d3 * d3);
    // loss_cls: sum_c bce(x,0) - sum_{distinct cid at this cell} x[cid]
    const float* cr = cls + ((size_t)b * NCELLS + c0) * NCLS_;
    float lc = 0.f;
    for (int c = 0; c < NCLS_; ++c) {
      const float xv = cr[c];
      lc += fmaxf(xv, 0.f) + log1pf(expf(-fabsf(xv)));
    }
    for (int g2 = 0; g2 < NG_; ++g2) {
      if (s_valid[g2] && s_cell[g2] == c0) {
        int first = 1;
        for (int g3 = 0; g3 < g2; ++g3)
          if (s_valid[g3] && s_cell[g3] == c0 && s_cid[g3] == s_cid[g2]) { first = 0; break; }
        if (first) lc -= cr[s_cid[g2]];
      }
    }
    v += acc + lc;
  }

  // ---- block reduce (wave-64 shfl, then LDS across 4 waves) ----
  #pragma unroll
  for (int off = 32; off; off >>= 1) v += __shfl_down(v, off, 64);
  __shared__ float s_part[4];
  if ((t & 63) == 0) s_part[t >> 6] = v;
  __syncthreads();
  if (t == 0)
    wsF[b * NBX + blockIdx.x] = s_part[0] + s_part[1] + s_part[2] + s_part[3];
}

// ---------------------------------------------------------------------------
// Kernel 2: deterministic final reduction of 32*48 = 1536 partials -> out[0].
// ---------------------------------------------------------------------------
__global__ __launch_bounds__(256)
void yolo_reduce(const float* __restrict__ wsF, float* __restrict__ out)
{
  const int t = threadIdx.x;
  float v = 0.f;
  for (int i = t; i < NB * NBX; i += 256) v += wsF[i];
  #pragma unroll
  for (int off = 32; off; off >>= 1) v += __shfl_down(v, off, 64);
  __shared__ float s_part[4];
  if ((t & 63) == 0) s_part[t >> 6] = v;
  __syncthreads();
  if (t == 0) out[0] = s_part[0] + s_part[1] + s_part[2] + s_part[3];
}

extern "C" void kernel_launch(void* const* d_in, const int* in_sizes, int n_in,
                              void* d_out, int out_size, void* d_ws, size_t ws_size,
                              hipStream_t stream) {
  const float* bbox   = (const float*)d_in[0];
  const float* conf   = (const float*)d_in[1];
  const float* cls    = (const float*)d_in[2];
  const float* labels = (const float*)d_in[3];
  const int*   img_h  = (const int*)d_in[4];
  const int*   img_w  = (const int*)d_in[5];

  float* out = (float*)d_out;
  float* wsF = (float*)d_ws;

  yolo_main<<<dim3(NBX, NB), dim3(256), 0, stream>>>(bbox, conf, cls, labels,
                                                     img_h, img_w, wsF);
  yolo_reduce<<<dim3(1), dim3(256), 0, stream>>>(wsF, out);
}

// Round 4
// 50.315 us; speedup vs baseline: 1.5888x; 1.2771x over previous
//
#include <hip/hip_runtime.h>
#include <math.h>

// ---- problem constants (from reference) ----
constexpr int NB = 32;
constexpr int NA_ = 3;
constexpr int NH_ = 64;
constexpr int NW_ = 64;
constexpr int NG_ = 24;
constexpr int NCLS_ = 80;
constexpr int NCELLS = NA_ * NH_ * NW_;   // 12288
constexpr int NBX = NCELLS / 256;         // 48
constexpr int NBLOCKS = NBX * NB;         // 1536
constexpr float IGNORE_THRE_ = 0.6f;

__device__ __constant__ float c_aw[9] = {10.f,16.f,33.f,30.f,62.f,59.f,116.f,156.f,373.f};
__device__ __constant__ float c_ah[9] = {13.f,30.f,23.f,61.f,45.f,119.f,90.f,198.f,326.f};

// self-resetting completion counter (module .data, NOT in d_ws -> never poisoned)
__device__ int g_cnt = 0;

__device__ __forceinline__ float softplus_neg_abs(float x) {
  return __logf(1.f + __expf(-fabsf(x)));   // log1p(exp(-|x|))
}
__device__ __forceinline__ float bce(float x, float t) {
  return fmaxf(x, 0.f) - x * t + softplus_neg_abs(x);
}

// ---------------------------------------------------------------------------
// Single kernel: GT processing + dense conf loss + sparse losses.
// grid = (48, 32), 256 threads; one thread per cell.
// Block partial -> wsF[b*48+bx]; last-arriving block reduces -> out[0].
// ---------------------------------------------------------------------------
__global__ __launch_bounds__(256)
void yolo_fused(const float* __restrict__ bbox,
                const float* __restrict__ conf,
                const float* __restrict__ cls,
                const float* __restrict__ labels,
                const int* __restrict__ img_h,
                const int* __restrict__ img_w,
                float* __restrict__ wsF,
                float* __restrict__ out)
{
  const int b = blockIdx.y;
  const int t = threadIdx.x;
  const int cell = blockIdx.x * 256 + t;   // 48*256 == 12288 exactly

  __shared__ float4 s_box[NG_];    // (g_l, g_t, g_r, g_b)
  __shared__ float s_ga06[NG_];    // 0.6 * gt area
  __shared__ int   s_cell[NG_];
  __shared__ int   s_cid[NG_];
  __shared__ int   s_valid[NG_];
  __shared__ int   s_win[NG_];
  __shared__ float s_upd[NG_][4];
  __shared__ float s_wv[NG_];
  __shared__ int   s_av;

  if (t < NG_) {
    const float* lab = labels + ((size_t)b * NG_ + t) * 5;
    const float cidf = lab[0];
    const float x = lab[1], y = lab[2], w = lab[3], h = lab[4];
    s_box[t] = make_float4(x - w * 0.5f, y - h * 0.5f, x + w * 0.5f, y + h * 0.5f);
    s_ga06[t] = 0.6f * w * h;
    // anchor IoU argmax (center (0,0) boxes): inter = min(w,aw)*min(h,ah)
    int best = 0; float bestv = -1.f;
    #pragma unroll
    for (int k = 0; k < 9; ++k) {
      const float inter = fminf(w, c_aw[k]) * fminf(h, c_ah[k]);
      const float uni = w * h + c_aw[k] * c_ah[k] - inter;
      const float v = __fdividef(inter, uni);
      if (v > bestv) { bestv = v; best = k; }   // first-max => strict >
    }
    const int valid = (best < NA_) ? 1 : 0;     // ANCH_LO == 0
    const int tn = best % NA_;
    const float gx = x * 0.125f, gy = y * 0.125f;
    const int ti = (int)gx, tj = (int)gy;
    s_cell[t]  = valid ? (tn * (NH_ * NW_) + tj * NW_ + ti) : -1;
    s_cid[t]   = (int)cidf;
    s_valid[t] = valid;
    const float aw = c_aw[tn], ah = c_ah[tn];
    s_upd[t][0] = gx - floorf(gx);
    s_upd[t][1] = gy - floorf(gy);
    s_upd[t][2] = logf(w / aw + 1e-8f);
    s_upd[t][3] = logf(h / ah + 1e-8f);
    const float img_area = (float)(*img_h) * (float)(*img_w);
    s_wv[t] = 2.f - w * h / img_area;
  }
  __syncthreads();

  // winner: valid and no LATER valid gt writes the same cell (last-write-wins)
  if (t < NG_) {
    int win = 0;
    if (s_valid[t]) {
      win = 1;
      for (int g2 = t + 1; g2 < NG_; ++g2)
        if (s_valid[g2] && s_cell[g2] == s_cell[t]) { win = 0; break; }
    }
    s_win[t] = win;
  }
  if (t == 32) {
    int av = 0;
    for (int g = 0; g < NG_; ++g) av |= s_valid[g];
    s_av = av;
  }
  __syncthreads();

  // ---- dense conf loss for this thread's cell ----
  const int a  = cell >> 12;
  const int hw = cell & 4095;
  const int hh = hw >> 6;
  const int ww = hw & 63;

  const float4 bb = *reinterpret_cast<const float4*>(bbox + ((size_t)b * NCELLS + cell) * 4);
  const float  cf = conf[(size_t)b * NCELLS + cell];

  const float sx = __fdividef(1.f, 1.f + __expf(-bb.x));
  const float sy = __fdividef(1.f, 1.f + __expf(-bb.y));
  const float px = (sx + (float)ww) * 8.f;
  const float py = (sy + (float)hh) * 8.f;
  const float pw = __expf(bb.z) * c_aw[a];
  const float ph = __expf(bb.w) * c_ah[a];
  const float p_l = px - pw * 0.5f, p_r = px + pw * 0.5f;
  const float p_t = py - ph * 0.5f, p_b = py + ph * 0.5f;
  const float pa06 = 0.6f * pw * ph;

  // ignore iff any IoU >= 0.6  <=>  inter >= 0.6*uni  <=>  1.6*inter >= 0.6*(pa+ga)
  int ignore = 0;
  #pragma unroll
  for (int g = 0; g < NG_; ++g) {
    const float4 gt = s_box[g];
    const float iw = fminf(p_r, gt.z) - fmaxf(p_l, gt.x);
    const float ih = fminf(p_b, gt.w) - fmaxf(p_t, gt.y);
    const float inter = fmaxf(iw, 0.f) * fmaxf(ih, 0.f);
    ignore |= (1.6f * inter >= pa06 + s_ga06[g]);
  }

  int gm = 0;
  #pragma unroll
  for (int g = 0; g < NG_; ++g) gm |= (s_win[g] & (s_cell[g] == cell));

  const int mask = gm | (!s_av) | (!ignore);
  float v = mask ? bce(cf, gm ? 1.f : 0.f) : 0.f;

  // ---- sparse losses (xy, wh, cls) at winner cells; only bx==0 blocks ----
  if (blockIdx.x == 0 && t < NG_ && s_win[t]) {
    const int c0 = s_cell[t];
    const float* bp = bbox + ((size_t)b * NCELLS + c0) * 4;
    const float wv = s_wv[t];
    float acc = wv * (bce(bp[0], s_upd[t][0]) + bce(bp[1], s_upd[t][1]));
    const float d2 = bp[2] - s_upd[t][2];
    const float d3 = bp[3] - s_upd[t][3];
    acc += 0.5f * wv * (d2 * d2 + d3 * d3);
    // loss_cls: sum_c bce(x,0) - sum_{distinct cid at this cell} x[cid]
    const float* cr = cls + ((size_t)b * NCELLS + c0) * NCLS_;
    float lc = 0.f;
    for (int c = 0; c < NCLS_; ++c) {
      const float xv = cr[c];
      lc += fmaxf(xv, 0.f) + softplus_neg_abs(xv);
    }
    for (int g2 = 0; g2 < NG_; ++g2) {
      if (s_valid[g2] && s_cell[g2] == c0) {
        int first = 1;
        for (int g3 = 0; g3 < g2; ++g3)
          if (s_valid[g3] && s_cell[g3] == c0 && s_cid[g3] == s_cid[g2]) { first = 0; break; }
        if (first) lc -= cr[s_cid[g2]];
      }
    }
    v += acc + lc;
  }

  // ---- block reduce (wave-64 shfl, then LDS across 4 waves) ----
  #pragma unroll
  for (int off = 32; off; off >>= 1) v += __shfl_down(v, off, 64);
  __shared__ float s_part[4];
  if ((t & 63) == 0) s_part[t >> 6] = v;
  __syncthreads();

  __shared__ int s_last;
  if (t == 0) {
    wsF[b * NBX + blockIdx.x] = s_part[0] + s_part[1] + s_part[2] + s_part[3];
    __threadfence();                       // make partial visible device-wide
    const int old = atomicAdd(&g_cnt, 1);  // device-scope
    s_last = (old == NBLOCKS - 1);
  }
  __syncthreads();

  // ---- last-arriving block: deterministic final reduction -> out[0] ----
  if (s_last) {
    __threadfence();   // acquire: partials written before the 1535 increments
    float r = 0.f;
    for (int i = t; i < NBLOCKS; i += 256) r += wsF[i];
    #pragma unroll
    for (int off = 32; off; off >>= 1) r += __shfl_down(r, off, 64);
    __shared__ float s_fin[4];
    if ((t & 63) == 0) s_fin[t >> 6] = r;
    __syncthreads();
    if (t == 0) {
      out[0] = s_fin[0] + s_fin[1] + s_fin[2] + s_fin[3];
      atomicExch(&g_cnt, 0);   // self-reset for next call / graph replay
    }
  }
}

extern "C" void kernel_launch(void* const* d_in, const int* in_sizes, int n_in,
                              void* d_out, int out_size, void* d_ws, size_t ws_size,
                              hipStream_t stream) {
  const float* bbox   = (const float*)d_in[0];
  const float* conf   = (const float*)d_in[1];
  const float* cls    = (const float*)d_in[2];
  const float* labels = (const float*)d_in[3];
  const int*   img_h  = (const int*)d_in[4];
  const int*   img_w  = (const int*)d_in[5];

  float* out = (float*)d_out;
  float* wsF = (float*)d_ws;

  yolo_fused<<<dim3(NBX, NB), dim3(256), 0, stream>>>(bbox, conf, cls, labels,
                                                      img_h, img_w, wsF, out);
}

// Round 5
// 37.894 us; speedup vs baseline: 2.1096x; 1.3278x over previous
//
#include <hip/hip_runtime.h>
#include <math.h>

// ---- problem constants (from reference) ----
constexpr int NB = 32;
constexpr int NA_ = 3;
constexpr int NH_ = 64;
constexpr int NW_ = 64;
constexpr int NG_ = 24;
constexpr int NCLS_ = 80;
constexpr int NCELLS = NA_ * NH_ * NW_;   // 12288
constexpr int NBX = 16;                   // blocks per image; 16*256*3 = 12288
constexpr int NBLOCKS = NBX * NB;         // 512
constexpr int PLANE = NH_ * NW_;          // 4096 cells per anchor

__device__ __constant__ float c_aw[9] = {10.f,16.f,33.f,30.f,62.f,59.f,116.f,156.f,373.f};
__device__ __constant__ float c_ah[9] = {13.f,30.f,23.f,61.f,45.f,119.f,90.f,198.f,326.f};

// self-resetting completion counter (module .data, NOT in d_ws -> never poisoned)
__device__ int g_cnt = 0;

__device__ __forceinline__ float softplus_neg_abs(float x) {
  return __logf(1.f + __expf(-fabsf(x)));   // log1p(exp(-|x|))
}
__device__ __forceinline__ float bce(float x, float t) {
  return fmaxf(x, 0.f) - x * t + softplus_neg_abs(x);
}

// ---------------------------------------------------------------------------
// Single kernel: GT processing + dense conf loss + sparse losses.
// grid = (16, 32), 256 threads; THREE cells per thread (one per anchor plane).
// Block partial -> wsF[b*16+bx]; last-arriving block reduces -> out[0].
// ---------------------------------------------------------------------------
__global__ __launch_bounds__(256)
void yolo_fused(const float* __restrict__ bbox,
                const float* __restrict__ conf,
                const float* __restrict__ cls,
                const float* __restrict__ labels,
                const int* __restrict__ img_h,
                const int* __restrict__ img_w,
                float* __restrict__ wsF,
                float* __restrict__ out)
{
  const int b = blockIdx.y;
  const int t = threadIdx.x;
  const int base = blockIdx.x * 256 + t;   // cell within anchor plane 0

  __shared__ float4 s_box[NG_];     // (g_l, g_t, g_r, g_b)
  __shared__ float  s_ga06[NG_];    // 0.6 * gt area
  __shared__ int    s_wincell[NG_]; // winner ? cell : -1
  __shared__ int    s_cell[NG_];
  __shared__ int    s_cid[NG_];
  __shared__ int    s_valid[NG_];
  __shared__ float  s_upd[NG_][4];
  __shared__ float  s_wv[NG_];
  __shared__ int    s_av;

  if (t < NG_) {
    const float* lab = labels + ((size_t)b * NG_ + t) * 5;
    const float cidf = lab[0];
    const float x = lab[1], y = lab[2], w = lab[3], h = lab[4];
    s_box[t] = make_float4(x - w * 0.5f, y - h * 0.5f, x + w * 0.5f, y + h * 0.5f);
    s_ga06[t] = 0.6f * w * h;
    // anchor IoU argmax (center (0,0) boxes): inter = min(w,aw)*min(h,ah)
    int best = 0; float bestv = -1.f;
    #pragma unroll
    for (int k = 0; k < 9; ++k) {
      const float inter = fminf(w, c_aw[k]) * fminf(h, c_ah[k]);
      const float uni = w * h + c_aw[k] * c_ah[k] - inter;
      const float v = __fdividef(inter, uni);
      if (v > bestv) { bestv = v; best = k; }   // first-max => strict >
    }
    const int valid = (best < NA_) ? 1 : 0;     // ANCH_LO == 0
    const int tn = best % NA_;
    const float gx = x * 0.125f, gy = y * 0.125f;
    const int ti = (int)gx, tj = (int)gy;
    s_cell[t]  = valid ? (tn * PLANE + tj * NW_ + ti) : -1;
    s_cid[t]   = (int)cidf;
    s_valid[t] = valid;
    const float aw = c_aw[tn], ah = c_ah[tn];
    s_upd[t][0] = gx - floorf(gx);
    s_upd[t][1] = gy - floorf(gy);
    s_upd[t][2] = logf(w / aw + 1e-8f);
    s_upd[t][3] = logf(h / ah + 1e-8f);
    const float img_area = (float)(*img_h) * (float)(*img_w);
    s_wv[t] = 2.f - w * h / img_area;
  }
  __syncthreads();

  // winner: valid and no LATER valid gt writes the same cell (last-write-wins)
  if (t < NG_) {
    int win = 0;
    if (s_valid[t]) {
      win = 1;
      for (int g2 = t + 1; g2 < NG_; ++g2)
        if (s_valid[g2] && s_cell[g2] == s_cell[t]) { win = 0; break; }
    }
    s_wincell[t] = win ? s_cell[t] : -1;
  }
  if (t == 32) {
    int av = 0;
    for (int g = 0; g < NG_; ++g) av |= s_valid[g];
    s_av = av;
  }
  __syncthreads();

  // ---- dense conf loss: 3 cells/thread (one per anchor plane) ----
  const int hh = (base >> 6) & 63;
  const int ww = base & 63;
  const float fx = (float)ww * 8.f;
  const float fy = (float)hh * 8.f;

  const size_t ib = (size_t)b * NCELLS;
  float v = 0.f;

  #pragma unroll
  for (int k = 0; k < NA_; ++k) {
    const int cell = k * PLANE + base;
    const float4 bb = *reinterpret_cast<const float4*>(bbox + (ib + cell) * 4);
    const float  cf = conf[ib + cell];

    const float px = __fdividef(8.f, 1.f + __expf(-bb.x)) + fx;
    const float py = __fdividef(8.f, 1.f + __expf(-bb.y)) + fy;
    const float pw = __expf(bb.z) * c_aw[k];
    const float ph = __expf(bb.w) * c_ah[k];
    const float p_l = px - pw * 0.5f, p_r = px + pw * 0.5f;
    const float p_t = py - ph * 0.5f, p_b = py + ph * 0.5f;
    const float pa06 = 0.6f * pw * ph;

    // ignore iff any IoU >= 0.6  <=>  1.6*inter >= 0.6*(pa+ga)
    int ignore = 0;
    #pragma unroll 8
    for (int g = 0; g < NG_; ++g) {
      const float4 gt = s_box[g];
      const float iw = fminf(p_r, gt.z) - fmaxf(p_l, gt.x);
      const float ih = fminf(p_b, gt.w) - fmaxf(p_t, gt.y);
      const float inter = fmaxf(iw, 0.f) * fmaxf(ih, 0.f);
      ignore |= (1.6f * inter >= pa06 + s_ga06[g]);
    }

    int gm = 0;
    #pragma unroll 8
    for (int g = 0; g < NG_; ++g) gm |= (s_wincell[g] == cell);

    const int mask = gm | (!s_av) | (!ignore);
    if (mask) v += bce(cf, gm ? 1.f : 0.f);
  }

  // ---- sparse losses (xy, wh, cls) at winner cells; only bx==0 blocks ----
  if (blockIdx.x == 0 && t < NG_ && s_wincell[t] >= 0) {
    const int c0 = s_cell[t];
    const float* bp = bbox + (ib + c0) * 4;
    const float wv = s_wv[t];
    float acc = wv * (bce(bp[0], s_upd[t][0]) + bce(bp[1], s_upd[t][1]));
    const float d2 = bp[2] - s_upd[t][2];
    const float d3 = bp[3] - s_upd[t][3];
    acc += 0.5f * wv * (d2 * d2 + d3 * d3);
    // loss_cls: sum_c bce(x,0) - sum_{distinct cid at this cell} x[cid]
    const float* cr = cls + (ib + c0) * NCLS_;
    float lc = 0.f;
    for (int c = 0; c < NCLS_; ++c) {
      const float xv = cr[c];
      lc += fmaxf(xv, 0.f) + softplus_neg_abs(xv);
    }
    for (int g2 = 0; g2 < NG_; ++g2) {
      if (s_valid[g2] && s_cell[g2] == c0) {
        int first = 1;
        for (int g3 = 0; g3 < g2; ++g3)
          if (s_valid[g3] && s_cell[g3] == c0 && s_cid[g3] == s_cid[g2]) { first = 0; break; }
        if (first) lc -= cr[s_cid[g2]];
      }
    }
    v += acc + lc;
  }

  // ---- block reduce (wave-64 shfl, then LDS across 4 waves) ----
  #pragma unroll
  for (int off = 32; off; off >>= 1) v += __shfl_down(v, off, 64);
  __shared__ float s_part[4];
  if ((t & 63) == 0) s_part[t >> 6] = v;
  __syncthreads();

  __shared__ int s_last;
  if (t == 0) {
    wsF[b * NBX + blockIdx.x] = s_part[0] + s_part[1] + s_part[2] + s_part[3];
    __threadfence();                       // make partial visible device-wide
    const int old = atomicAdd(&g_cnt, 1);  // device-scope
    s_last = (old == NBLOCKS - 1);
  }
  __syncthreads();

  // ---- last-arriving block: deterministic final reduction -> out[0] ----
  if (s_last) {
    __threadfence();   // acquire: partials written before the increments
    float r = 0.f;
    for (int i = t; i < NBLOCKS; i += 256) r += wsF[i];
    #pragma unroll
    for (int off = 32; off; off >>= 1) r += __shfl_down(r, off, 64);
    __shared__ float s_fin[4];
    if ((t & 63) == 0) s_fin[t >> 6] = r;
    __syncthreads();
    if (t == 0) {
      out[0] = s_fin[0] + s_fin[1] + s_fin[2] + s_fin[3];
      atomicExch(&g_cnt, 0);   // self-reset for next call / graph replay
    }
  }
}

extern "C" void kernel_launch(void* const* d_in, const int* in_sizes, int n_in,
                              void* d_out, int out_size, void* d_ws, size_t ws_size,
                              hipStream_t stream) {
  const float* bbox   = (const float*)d_in[0];
  const float* conf   = (const float*)d_in[1];
  const float* cls    = (const float*)d_in[2];
  const float* labels = (const float*)d_in[3];
  const int*   img_h  = (const int*)d_in[4];
  const int*   img_w  = (const int*)d_in[5];

  float* out = (float*)d_out;
  float* wsF = (float*)d_ws;

  yolo_fused<<<dim3(NBX, NB), dim3(256), 0, stream>>>(bbox, conf, cls, labels,
                                                      img_h, img_w, wsF, out);
}

// Round 6
// 36.460 us; speedup vs baseline: 2.1925x; 1.0393x over previous
//
#include <hip/hip_runtime.h>
#include <math.h>

// ---- problem constants (from reference) ----
constexpr int NB = 32;
constexpr int NA_ = 3;
constexpr int NH_ = 64;
constexpr int NW_ = 64;
constexpr int NG_ = 24;
constexpr int NCLS_ = 80;
constexpr int NCELLS = NA_ * NH_ * NW_;   // 12288
constexpr int NBX = 16;                   // blocks per image; 16*256*3 = 12288
constexpr int NBLOCKS = NBX * NB;         // 512
constexpr int PLANE = NH_ * NW_;          // 4096 cells per anchor

__device__ __constant__ float c_aw[9] = {10.f,16.f,33.f,30.f,62.f,59.f,116.f,156.f,373.f};
__device__ __constant__ float c_ah[9] = {13.f,30.f,23.f,61.f,45.f,119.f,90.f,198.f,326.f};

// self-resetting completion counter (module .data, NOT in d_ws -> never poisoned)
__device__ int g_cnt = 0;

__device__ __forceinline__ float softplus_neg_abs(float x) {
  return __logf(1.f + __expf(-fabsf(x)));   // log1p(exp(-|x|))
}
__device__ __forceinline__ float bce(float x, float t) {
  return fmaxf(x, 0.f) - x * t + softplus_neg_abs(x);
}

// ---------------------------------------------------------------------------
// Single kernel: GT processing + dense conf loss + sparse losses.
// grid = (16, 32), 256 threads; THREE cells per thread (one per anchor plane).
// Global loads issued at entry (hide HBM latency under GT setup); single
// 24-GT LDS loop serves all 3 anchors. Block partial -> wsF; last block
// reduces -> out[0].
// ---------------------------------------------------------------------------
__global__ __launch_bounds__(256)
void yolo_fused(const float* __restrict__ bbox,
                const float* __restrict__ conf,
                const float* __restrict__ cls,
                const float* __restrict__ labels,
                const int* __restrict__ img_h,
                const int* __restrict__ img_w,
                float* __restrict__ wsF,
                float* __restrict__ out)
{
  const int b = blockIdx.y;
  const int t = threadIdx.x;
  const int base = blockIdx.x * 256 + t;   // cell within anchor plane 0
  const size_t ib = (size_t)b * NCELLS;

  // ---- issue all global loads up-front (latency hides under GT setup) ----
  const float4 bb0 = *reinterpret_cast<const float4*>(bbox + (ib + 0 * PLANE + base) * 4);
  const float4 bb1 = *reinterpret_cast<const float4*>(bbox + (ib + 1 * PLANE + base) * 4);
  const float4 bb2 = *reinterpret_cast<const float4*>(bbox + (ib + 2 * PLANE + base) * 4);
  const float  cf0 = conf[ib + 0 * PLANE + base];
  const float  cf1 = conf[ib + 1 * PLANE + base];
  const float  cf2 = conf[ib + 2 * PLANE + base];

  __shared__ float4 s_box[NG_];     // (g_l, g_t, g_r, g_b)
  __shared__ float  s_ga06[NG_];    // 0.6 * gt area
  __shared__ int    s_wincell[NG_]; // winner ? cell : -1
  __shared__ int    s_cell[NG_];
  __shared__ int    s_cid[NG_];
  __shared__ int    s_valid[NG_];
  __shared__ float  s_upd[NG_][4];
  __shared__ float  s_wv[NG_];
  __shared__ int    s_av;

  if (t < NG_) {
    const float* lab = labels + ((size_t)b * NG_ + t) * 5;
    const float cidf = lab[0];
    const float x = lab[1], y = lab[2], w = lab[3], h = lab[4];
    s_box[t] = make_float4(x - w * 0.5f, y - h * 0.5f, x + w * 0.5f, y + h * 0.5f);
    s_ga06[t] = 0.6f * w * h;
    // anchor IoU argmax (center (0,0) boxes): inter = min(w,aw)*min(h,ah)
    int best = 0; float bestv = -1.f;
    #pragma unroll
    for (int k = 0; k < 9; ++k) {
      const float inter = fminf(w, c_aw[k]) * fminf(h, c_ah[k]);
      const float uni = w * h + c_aw[k] * c_ah[k] - inter;
      const float v = __fdividef(inter, uni);
      if (v > bestv) { bestv = v; best = k; }   // first-max => strict >
    }
    const int valid = (best < NA_) ? 1 : 0;     // ANCH_LO == 0
    const int tn = best % NA_;
    const float gx = x * 0.125f, gy = y * 0.125f;
    const int ti = (int)gx, tj = (int)gy;
    s_cell[t]  = valid ? (tn * PLANE + tj * NW_ + ti) : -1;
    s_cid[t]   = (int)cidf;
    s_valid[t] = valid;
    const float aw = c_aw[tn], ah = c_ah[tn];
    s_upd[t][0] = gx - floorf(gx);
    s_upd[t][1] = gy - floorf(gy);
    s_upd[t][2] = __logf(w / aw + 1e-8f);
    s_upd[t][3] = __logf(h / ah + 1e-8f);
    const float img_area = (float)(*img_h) * (float)(*img_w);
    s_wv[t] = 2.f - w * h / img_area;
  }
  __syncthreads();

  // winner: valid and no LATER valid gt writes the same cell (last-write-wins)
  if (t < NG_) {
    int win = 0;
    if (s_valid[t]) {
      win = 1;
      for (int g2 = t + 1; g2 < NG_; ++g2)
        if (s_valid[g2] && s_cell[g2] == s_cell[t]) { win = 0; break; }
    }
    s_wincell[t] = win ? s_cell[t] : -1;
  }
  if (t == 32) {
    int av = 0;
    for (int g = 0; g < NG_; ++g) av |= s_valid[g];
    s_av = av;
  }
  __syncthreads();

  // ---- decode all 3 anchors into registers ----
  const float fx = (float)(base & 63) * 8.f;
  const float fy = (float)((base >> 6) & 63) * 8.f;

  float p_l[NA_], p_r[NA_], p_t[NA_], p_b[NA_], pa06[NA_];
  {
    const float4 bbs[NA_] = {bb0, bb1, bb2};
    #pragma unroll
    for (int k = 0; k < NA_; ++k) {
      const float px = __fdividef(8.f, 1.f + __expf(-bbs[k].x)) + fx;
      const float py = __fdividef(8.f, 1.f + __expf(-bbs[k].y)) + fy;
      const float pw = __expf(bbs[k].z) * c_aw[k];
      const float ph = __expf(bbs[k].w) * c_ah[k];
      p_l[k] = px - pw * 0.5f; p_r[k] = px + pw * 0.5f;
      p_t[k] = py - ph * 0.5f; p_b[k] = py + ph * 0.5f;
      pa06[k] = 0.6f * pw * ph;
    }
  }

  // ---- single 24-GT loop: ignore + target-membership for all 3 anchors ----
  int ig0 = 0, ig1 = 0, ig2 = 0;
  int gm0 = 0, gm1 = 0, gm2 = 0;
  const int cell1 = PLANE + base, cell2 = 2 * PLANE + base;
  #pragma unroll 6
  for (int g = 0; g < NG_; ++g) {
    const float4 gt = s_box[g];
    const float ga = s_ga06[g];
    const int   wc = s_wincell[g];
    {
      const float iw = fminf(p_r[0], gt.z) - fmaxf(p_l[0], gt.x);
      const float ih = fminf(p_b[0], gt.w) - fmaxf(p_t[0], gt.y);
      ig0 |= (1.6f * (fmaxf(iw, 0.f) * fmaxf(ih, 0.f)) >= pa06[0] + ga);
    }
    {
      const float iw = fminf(p_r[1], gt.z) - fmaxf(p_l[1], gt.x);
      const float ih = fminf(p_b[1], gt.w) - fmaxf(p_t[1], gt.y);
      ig1 |= (1.6f * (fmaxf(iw, 0.f) * fmaxf(ih, 0.f)) >= pa06[1] + ga);
    }
    {
      const float iw = fminf(p_r[2], gt.z) - fmaxf(p_l[2], gt.x);
      const float ih = fminf(p_b[2], gt.w) - fmaxf(p_t[2], gt.y);
      ig2 |= (1.6f * (fmaxf(iw, 0.f) * fmaxf(ih, 0.f)) >= pa06[2] + ga);
    }
    gm0 |= (wc == base);
    gm1 |= (wc == cell1);
    gm2 |= (wc == cell2);
  }

  const int nav = !s_av;
  float v = 0.f;
  if (gm0 | nav | !ig0) v += bce(cf0, gm0 ? 1.f : 0.f);
  if (gm1 | nav | !ig1) v += bce(cf1, gm1 ? 1.f : 0.f);
  if (gm2 | nav | !ig2) v += bce(cf2, gm2 ? 1.f : 0.f);

  // ---- sparse losses (xy, wh, cls) at winner cells; only bx==0 blocks ----
  if (blockIdx.x == 0 && t < NG_ && s_wincell[t] >= 0) {
    const int c0 = s_cell[t];
    const float* bp = bbox + (ib + c0) * 4;
    const float wv = s_wv[t];
    float acc = wv * (bce(bp[0], s_upd[t][0]) + bce(bp[1], s_upd[t][1]));
    const float d2 = bp[2] - s_upd[t][2];
    const float d3 = bp[3] - s_upd[t][3];
    acc += 0.5f * wv * (d2 * d2 + d3 * d3);
    // loss_cls: sum_c bce(x,0) - sum_{distinct cid at this cell} x[cid]
    const float* cr = cls + (ib + c0) * NCLS_;
    float lc = 0.f;
    for (int c = 0; c < NCLS_; ++c) {
      const float xv = cr[c];
      lc += fmaxf(xv, 0.f) + softplus_neg_abs(xv);
    }
    for (int g2 = 0; g2 < NG_; ++g2) {
      if (s_valid[g2] && s_cell[g2] == c0) {
        int first = 1;
        for (int g3 = 0; g3 < g2; ++g3)
          if (s_valid[g3] && s_cell[g3] == c0 && s_cid[g3] == s_cid[g2]) { first = 0; break; }
        if (first) lc -= cr[s_cid[g2]];
      }
    }
    v += acc + lc;
  }

  // ---- block reduce (wave-64 shfl, then LDS across 4 waves) ----
  #pragma unroll
  for (int off = 32; off; off >>= 1) v += __shfl_down(v, off, 64);
  __shared__ float s_part[4];
  if ((t & 63) == 0) s_part[t >> 6] = v;
  __syncthreads();

  __shared__ int s_last;
  if (t == 0) {
    wsF[b * NBX + blockIdx.x] = s_part[0] + s_part[1] + s_part[2] + s_part[3];
    __threadfence();                       // make partial visible device-wide
    const int old = atomicAdd(&g_cnt, 1);  // device-scope
    s_last = (old == NBLOCKS - 1);
  }
  __syncthreads();

  // ---- last-arriving block: deterministic final reduction -> out[0] ----
  if (s_last) {
    __threadfence();   // acquire: partials written before the increments
    float r = 0.f;
    for (int i = t; i < NBLOCKS; i += 256) r += wsF[i];
    #pragma unroll
    for (int off = 32; off; off >>= 1) r += __shfl_down(r, off, 64);
    __shared__ float s_fin[4];
    if ((t & 63) == 0) s_fin[t >> 6] = r;
    __syncthreads();
    if (t == 0) {
      out[0] = s_fin[0] + s_fin[1] + s_fin[2] + s_fin[3];
      atomicExch(&g_cnt, 0);   // self-reset for next call / graph replay
    }
  }
}

extern "C" void kernel_launch(void* const* d_in, const int* in_sizes, int n_in,
                              void* d_out, int out_size, void* d_ws, size_t ws_size,
                              hipStream_t stream) {
  const float* bbox   = (const float*)d_in[0];
  const float* conf   = (const float*)d_in[1];
  const float* cls    = (const float*)d_in[2];
  const float* labels = (const float*)d_in[3];
  const int*   img_h  = (const int*)d_in[4];
  const int*   img_w  = (const int*)d_in[5];

  float* out = (float*)d_out;
  float* wsF = (float*)d_ws;

  yolo_fused<<<dim3(NBX, NB), dim3(256), 0, stream>>>(bbox, conf, cls, labels,
                                                      img_h, img_w, wsF, out);
}